// Round 1
// 772.669 us; speedup vs baseline: 1.0081x; 1.0081x over previous
//
#include <hip/hip_runtime.h>

// HBVMulTDET: 365-step HBV scan over [Ngrid=2000 x NMUL=16] chains + NMUL-mean
// + 15-tap gamma-UH routing conv.
// R1: routing conv deferred out of the serial scan (qavg to LDS, parallel conv).
// R2: scan-iteration overhead attack (completion time = one wave's serial loop;
//     500 waves on 1024 SIMDs -> no TLP, so only per-step issue/stall count matters):
//  - forcings repacked [t][gl][4]: one ds_read_b128/step, prefetched 2 steps
//    ahead (latency hidden under a full step; no per-step register copies)
//  - DPP mean cut 4 stages -> 2 (store four 4-group sums; conv finishes the
//    reduction as (s0+s1)+(s2+s3) -- BIT-IDENTICAL to the old ror4/ror8 path)
//  - scan unrolled x2 (half the loop control; q-path of step t schedules under
//    the state chain of step t+1)
// Layout: block=64 threads = 4 grids x 16 muls; thread = (grid gl, mul m).

#define LENF 15

__device__ __forceinline__ float flog2(float x) { return __builtin_amdgcn_logf(x); }
__device__ __forceinline__ float fexp2(float x) { return __builtin_amdgcn_exp2f(x); }
__device__ __forceinline__ float fpow(float x, float y) { return fexp2(y * flog2(x)); }

template <int CTRL>
__device__ __forceinline__ float dpp_add(float x) {
    int p = __builtin_amdgcn_update_dpp(0, __float_as_int(x), CTRL, 0xF, 0xF, true);
    return x + __int_as_float(p);
}

__global__ __launch_bounds__(64, 1) void hbv_kernel(
    const float* __restrict__ x,        // [Nstep, Ngrid, 3]
    const float* __restrict__ praw,     // [Nstep, Ngrid, 14, 16]
    const float* __restrict__ convp,    // [Ngrid, 2]
    float* __restrict__ out,            // [Nstep, Ngrid]
    int Nstep, int Ngrid)
{
    const int tid = threadIdx.x;
    const int gl  = tid >> 4;     // grid within block: 0..3
    const int m   = tid & 15;     // mul component: 0..15
    const int g0  = blockIdx.x * 4;
    const int g   = g0 + gl;

    // ---- LDS: forcings [t][gl][4] (P,T,PET,pad -> 16B aligned per (t,gl))
    //          qbuf     [t][gl][4] (four 4-lane partial sums per (t,gl))
    __shared__ float fbuf[368 * 16];
    __shared__ float qbuf[368 * 16];

    // stage forcings: thread j covers (t, gg); one ds_write_b128 each
    for (int j = tid; j < Nstep * 4; j += 64) {
        int t = j >> 2, gg = j & 3;
        const float* s = x + ((size_t)t * Ngrid + (g0 + gg)) * 3;
        float4 v; v.x = s[0]; v.y = s[1]; v.z = s[2]; v.w = 0.0f;
        *(float4*)(fbuf + t * 16 + gg * 4) = v;
    }

    // ---- static params: praw[Nstep-1, g, i, m] scaled to bounds
    const float lo[14] = {1.0f, 50.0f, 0.05f, 0.01f, 0.001f, 0.2f, 0.0f, 0.0f,
                          -2.5f, 0.5f, 0.0f, 0.0f, 0.3f, 0.0f};
    const float hi[14] = {6.0f, 1000.0f, 0.9f, 0.5f, 0.2f, 1.0f, 10.0f, 100.0f,
                          2.5f, 10.0f, 0.1f, 0.2f, 5.0f, 1.0f};
    float par[14];
    {
        const float* pr = praw + ((size_t)(Nstep - 1) * Ngrid + g) * 14 * 16 + m;
        #pragma unroll
        for (int i = 0; i < 14; ++i)
            par[i] = fmaf(pr[i * 16], hi[i] - lo[i], lo[i]);
    }
    const float pBETA = par[0], pFC = par[1], pK0 = par[2], pK1 = par[3], pK2 = par[4],
                pLP = par[5], pPERC = par[6], pUZL = par[7], pTT = par[8], pCFMAX = par[9],
                pCFR = par[10], pCWH = par[11], pBETAET = par[12], pC = par[13];
    const float invFC    = 1.0f / pFC;
    const float invLPFC  = 1.0f / (pLP * pFC);
    const float cfrcfmax = pCFR * pCFMAX;

    // ---- gamma unit hydrograph (denominator cancels under normalization)
    float uh[LENF];
    {
        float a  = convp[g * 2 + 0] * 2.9f;
        float bb = convp[g * 2 + 1] * 6.5f;
        float aa = fmaxf(a, 0.0f) + 0.1f;
        float th = fmaxf(bb, 0.0f) + 0.5f;
        float am1 = aa - 1.0f;
        float c1  = 1.4426950408889634f / th;  // log2(e)/theta
        const float L[LENF] = {  // log2(k + 0.5)
            -1.0f, 0.5849625007f, 1.3219280949f, 1.8073549221f, 2.1699250014f,
            2.4594316186f, 2.7004397181f, 2.9068905956f, 3.0874628413f, 3.2479275134f,
            3.3923174228f, 3.5235619561f, 3.6438561898f, 3.7548875022f, 3.8579809951f};
        float s = 0.0f;
        #pragma unroll
        for (int k = 0; k < LENF; ++k) {
            float t = (float)k + 0.5f;
            float w = fexp2(fmaf(am1, L[k], -t * c1));  // t^(aa-1) * exp(-t/theta)
            uh[k] = w;
            s += w;
        }
        float is = 1.0f / s;
        #pragma unroll
        for (int k = 0; k < LENF; ++k) uh[k] *= is;
    }

    __syncthreads();

    // ---- serial scan, unrolled x2, forcings prefetched 2 steps ahead
    const float NZ = 1e-5f;
    float SNOWPACK = 1e-3f, MELTWATER = 1e-3f, SM = 1e-3f, SUZ = 1e-3f, SLZ = 1e-3f;

    auto STEP = [&](float4 f, float* qdst) {
        float P = f.x, T = f.y, PET = f.z;
        bool warm  = (T >= pTT);
        float RAIN = warm ? P : 0.0f;
        float SNOW = warm ? 0.0f : P;
        SNOWPACK += SNOW;
        float melt = fminf(fmaxf(pCFMAX * (T - pTT), 0.0f), SNOWPACK);
        MELTWATER += melt;
        SNOWPACK = fmaxf(SNOWPACK - melt, NZ);
        float refr = fminf(fmaxf(cfrcfmax * (pTT - T), 0.0f), MELTWATER);
        SNOWPACK += refr;
        MELTWATER = fmaxf(MELTWATER - refr, NZ);
        float tosoil = fmaxf(fmaf(-pCWH, SNOWPACK, MELTWATER), 0.0f);
        MELTWATER = fmaxf(MELTWATER - tosoil, NZ);
        float sw = fminf(fpow(SM * invFC, pBETA), 1.0f);
        float rt = RAIN + tosoil;
        float recharge = rt * sw;
        SM = SM + rt - recharge;
        float excess = fmaxf(SM - pFC, 0.0f);
        SM = fmaxf(SM - excess, NZ);
        float ev = fminf(fpow(SM * invLPFC, pBETAET), 1.0f);
        float ETact = fminf(SM, PET * ev);
        SM = fmaxf(SM - ETact, NZ);
        float cap = fminf(SLZ, pC * SLZ * (1.0f - fminf(SM * invFC, 1.0f)));
        SM  = fmaxf(SM + cap, NZ);
        SLZ = fmaxf(SLZ - cap, NZ);
        SUZ = SUZ + recharge + excess;
        float perc = fminf(SUZ, pPERC);
        SUZ -= perc;
        float Q0 = pK0 * fmaxf(SUZ - pUZL, 0.0f);
        SUZ -= Q0;
        float Q1 = pK1 * SUZ;
        SUZ -= Q1;
        SLZ += perc;
        float Q2 = pK2 * SLZ;
        SLZ -= Q2;
        float q = Q0 + Q1 + Q2;

        // partial mean: 2 DPP stages -> lanes {0,4,8,12} hold disjoint 4-sums
        float qs = dpp_add<0x121>(q);   // row_ror:1
        qs = dpp_add<0x122>(qs);        // row_ror:2
        if ((m & 3) == 0) qdst[m >> 2] = qs;
    };

    const float4* fv = (const float4*)fbuf + gl;   // index by t*4
    float* qd = qbuf + gl * 4;                     // advances 16 floats per t
    float4 fA = fv[0];
    float4 fB = fv[4];
    int t = 0;
    for (; t + 2 < Nstep; t += 2) {
        STEP(fA, qd);                // step t
        fA = fv[(t + 2) * 4];        // prefetch t+2 (used next iteration)
        STEP(fB, qd + 16);           // step t+1
        fB = fv[(t + 3) * 4];        // prefetch t+3 (pad rows make this safe)
        qd += 32;
    }
    STEP(fA, qd);
    if (t + 1 < Nstep) STEP(fB, qd + 16);
    __syncthreads();

    // ---- parallel routing conv: lane m covers a contiguous t-chunk of its grid
    const int chunk = (Nstep + 15) >> 4;          // 23 for Nstep=365
    int t0 = m * chunk;
    int t1 = min(t0 + chunk, Nstep);
    const float4* qv = (const float4*)qbuf + gl;
    float w[LENF];
    #pragma unroll
    for (int k = 0; k < LENF; ++k) {
        int tt = t0 - k;
        if (tt >= 0) {
            float4 r = qv[tt * 4];
            w[k] = ((r.x + r.y) + (r.z + r.w)) * 0.0625f;  // == old ror4+ror8 order
        } else {
            w[k] = 0.0f;
        }
    }
    for (int tt = t0; tt < t1; ++tt) {
        float acc = 0.0f;
        #pragma unroll
        for (int k = 0; k < LENF; ++k) acc = fmaf(uh[k], w[k], acc);
        out[(size_t)tt * Ngrid + g] = acc;
        #pragma unroll
        for (int k = LENF - 1; k > 0; --k) w[k] = w[k - 1];
        if (tt + 1 < Nstep) {
            float4 r = qv[(tt + 1) * 4];
            w[0] = ((r.x + r.y) + (r.z + r.w)) * 0.0625f;
        } else {
            w[0] = 0.0f;
        }
    }
}

extern "C" void kernel_launch(void* const* d_in, const int* in_sizes, int n_in,
                              void* d_out, int out_size, void* d_ws, size_t ws_size,
                              hipStream_t stream) {
    const float* x     = (const float*)d_in[0];
    // d_in[1] = c_hydro_model — unused by the reference
    const float* praw  = (const float*)d_in[2];
    const float* convp = (const float*)d_in[3];
    float* out = (float*)d_out;

    int Ngrid = in_sizes[3] / 2;                 // conv_params_hydro: [Ngrid, 2]
    int Nstep = in_sizes[0] / (3 * Ngrid);       // x: [Nstep, Ngrid, 3]
    int blocks = Ngrid / 4;                      // 4 grids per 64-thread block

    hbv_kernel<<<blocks, 64, 0, stream>>>(x, praw, convp, out, Nstep, Ngrid);
}

// Round 3
// 754.071 us; speedup vs baseline: 1.0330x; 1.0247x over previous
//
#include <hip/hip_runtime.h>

// HBVMulTDET: 365-step HBV scan over [Ngrid=2000 x NMUL=16] chains + NMUL-mean
// + 15-tap gamma-UH routing conv.
// R1: routing conv deferred out of the serial scan (qavg to LDS, parallel conv).
// R2: forcings [t][gl][4] + b128 prefetch, 2-stage DPP partial mean, unroll x2.
// R3: cross-step latency overlap attack. Wall time = one wave's serial loop
//     (500 waves / 1024 SIMDs, no TLP); R2's -6us showed cycle cuts pay
//     linearly. So: scan unrolled x4 (3 of 4 step boundaries become compiler-
//     schedulable overlap windows: step t+1's snow head only needs SNOWPACK/
//     MELTWATER, final early in step t, so it runs under t's soil/SUZ/SLZ tail
//     and the two fpow latencies), q-partials batched to ONE masked
//     ds_write_b128 per 4 steps (removes 3 exec-mask dances + 3 LDS ops),
//     forcings prefetched one full 4-step iteration ahead, UH calc moved off
//     the pre-scan path. Per-step math order IDENTICAL -> absmax unchanged.
// R3-resubmit: Round-2 bench died to container-infra failure (no miscompare
//     evidence; push timing showed a 2h input push). Kernel re-audited for
//     bounds/LDS safety (fbuf 23.25KiB + qbuf 23.25KiB; all indices checked)
//     and resubmitted unchanged for measurement.
// Layout: block=64 threads = 4 grids x 16 muls; thread = (grid gl, mul m).

#define LENF 15

__device__ __forceinline__ float flog2(float x) { return __builtin_amdgcn_logf(x); }
__device__ __forceinline__ float fexp2(float x) { return __builtin_amdgcn_exp2f(x); }
__device__ __forceinline__ float fpow(float x, float y) { return fexp2(y * flog2(x)); }

template <int CTRL>
__device__ __forceinline__ float dpp_add(float x) {
    int p = __builtin_amdgcn_update_dpp(0, __float_as_int(x), CTRL, 0xF, 0xF, true);
    return x + __int_as_float(p);
}

__global__ __launch_bounds__(64, 1) void hbv_kernel(
    const float* __restrict__ x,        // [Nstep, Ngrid, 3]
    const float* __restrict__ praw,     // [Nstep, Ngrid, 14, 16]
    const float* __restrict__ convp,    // [Ngrid, 2]
    float* __restrict__ out,            // [Nstep, Ngrid]
    int Nstep, int Ngrid)
{
    const int tid = threadIdx.x;
    const int gl  = tid >> 4;     // grid within block: 0..3
    const int m   = tid & 15;     // mul component: 0..15
    const int g0  = blockIdx.x * 4;
    const int g   = g0 + gl;

    // ---- LDS ----
    // fbuf: forcings [t][gl][4] (P,T,PET,pad), 372 t-rows (prefetch overrun pad)
    // qbuf: q partial sums [tb][gl][slot][tl]: tb = t>>2, slot s = 4-lane-group
    //       sum of mul lanes 4s..4s+3, tl = t&3. 93 tb rows (91 full + tail + pad).
    __shared__ float fbuf[372 * 16];
    __shared__ float qbuf[93 * 64];

    // stage forcings: thread j covers (t, gg); one ds_write_b128 each
    for (int j = tid; j < Nstep * 4; j += 64) {
        int t = j >> 2, gg = j & 3;
        const float* s = x + ((size_t)t * Ngrid + (g0 + gg)) * 3;
        float4 v; v.x = s[0]; v.y = s[1]; v.z = s[2]; v.w = 0.0f;
        *(float4*)(fbuf + t * 16 + gg * 4) = v;
    }

    // ---- static params: praw[Nstep-1, g, i, m] scaled to bounds
    const float lo[14] = {1.0f, 50.0f, 0.05f, 0.01f, 0.001f, 0.2f, 0.0f, 0.0f,
                          -2.5f, 0.5f, 0.0f, 0.0f, 0.3f, 0.0f};
    const float hi[14] = {6.0f, 1000.0f, 0.9f, 0.5f, 0.2f, 1.0f, 10.0f, 100.0f,
                          2.5f, 10.0f, 0.1f, 0.2f, 5.0f, 1.0f};
    float par[14];
    {
        const float* pr = praw + ((size_t)(Nstep - 1) * Ngrid + g) * 14 * 16 + m;
        #pragma unroll
        for (int i = 0; i < 14; ++i)
            par[i] = fmaf(pr[i * 16], hi[i] - lo[i], lo[i]);
    }
    const float pBETA = par[0], pFC = par[1], pK0 = par[2], pK1 = par[3], pK2 = par[4],
                pLP = par[5], pPERC = par[6], pUZL = par[7], pTT = par[8], pCFMAX = par[9],
                pCFR = par[10], pCWH = par[11], pBETAET = par[12], pC = par[13];
    const float invFC    = 1.0f / pFC;
    const float invLPFC  = 1.0f / (pLP * pFC);
    const float cfrcfmax = pCFR * pCFMAX;

    // issue convp loads early; UH math deferred to after the scan
    const float cpa = convp[g * 2 + 0];
    const float cpb = convp[g * 2 + 1];

    __syncthreads();

    // ---- serial scan, unrolled x4, forcings prefetched one iteration ahead
    const float NZ = 1e-5f;
    float SNOWPACK = 1e-3f, MELTWATER = 1e-3f, SM = 1e-3f, SUZ = 1e-3f, SLZ = 1e-3f;

    auto STEP = [&](float4 f) -> float {
        float P = f.x, T = f.y, PET = f.z;
        bool warm  = (T >= pTT);
        float RAIN = warm ? P : 0.0f;
        float SNOW = warm ? 0.0f : P;
        SNOWPACK += SNOW;
        float melt = fminf(fmaxf(pCFMAX * (T - pTT), 0.0f), SNOWPACK);
        MELTWATER += melt;
        SNOWPACK = fmaxf(SNOWPACK - melt, NZ);
        float refr = fminf(fmaxf(cfrcfmax * (pTT - T), 0.0f), MELTWATER);
        SNOWPACK += refr;
        MELTWATER = fmaxf(MELTWATER - refr, NZ);
        float tosoil = fmaxf(fmaf(-pCWH, SNOWPACK, MELTWATER), 0.0f);
        MELTWATER = fmaxf(MELTWATER - tosoil, NZ);
        float sw = fminf(fpow(SM * invFC, pBETA), 1.0f);
        float rt = RAIN + tosoil;
        float recharge = rt * sw;
        SM = SM + rt - recharge;
        float excess = fmaxf(SM - pFC, 0.0f);
        SM = fmaxf(SM - excess, NZ);
        float ev = fminf(fpow(SM * invLPFC, pBETAET), 1.0f);
        float ETact = fminf(SM, PET * ev);
        SM = fmaxf(SM - ETact, NZ);
        float cap = fminf(SLZ, pC * SLZ * (1.0f - fminf(SM * invFC, 1.0f)));
        SM  = fmaxf(SM + cap, NZ);
        SLZ = fmaxf(SLZ - cap, NZ);
        SUZ = SUZ + recharge + excess;
        float perc = fminf(SUZ, pPERC);
        SUZ -= perc;
        float Q0 = pK0 * fmaxf(SUZ - pUZL, 0.0f);
        SUZ -= Q0;
        float Q1 = pK1 * SUZ;
        SUZ -= Q1;
        SLZ += perc;
        float Q2 = pK2 * SLZ;
        SLZ -= Q2;
        float q = Q0 + Q1 + Q2;
        // partial mean: 2 DPP stages -> lanes {0,4,8,12} hold disjoint 4-sums
        float qs = dpp_add<0x121>(q);   // row_ror:1
        qs = dpp_add<0x122>(qs);        // row_ror:2
        return qs;
    };

    const float4* fv = (const float4*)fbuf + gl;      // index by t*4
    float4 fA = fv[0], fB = fv[4], fC = fv[8], fD = fv[12];

    const bool qlane = ((m & 3) == 0);
    float* qw = qbuf + gl * 16 + (m >> 2) * 4;        // this lane's slot base
    const int FB = Nstep >> 2;                        // full 4-step blocks (91)

    int t = 0;
    for (int tb = 0; tb < FB; ++tb, t += 4) {
        float q0 = STEP(fA); fA = fv[(t + 4) * 4];    // prefetch next iter
        float q1 = STEP(fB); fB = fv[(t + 5) * 4];
        float q2 = STEP(fC); fC = fv[(t + 6) * 4];
        float q3 = STEP(fD); fD = fv[(t + 7) * 4];
        if (qlane) {
            float4 qv; qv.x = q0; qv.y = q1; qv.z = q2; qv.w = q3;
            *(float4*)(qw + tb * 64) = qv;            // one b128 per 4 steps
        }
    }
    // tail (Nstep=365 -> 1 step; handles up to 3)
    int rem = Nstep - t;
    if (rem > 0) { float q0 = STEP(fA); if (qlane) qw[FB * 64 + 0] = q0; }
    if (rem > 1) { float q1 = STEP(fB); if (qlane) qw[FB * 64 + 1] = q1; }
    if (rem > 2) { float q2 = STEP(fC); if (qlane) qw[FB * 64 + 2] = q2; }

    // ---- gamma unit hydrograph (deferred; denominator cancels when normalized)
    float uh[LENF];
    {
        float a  = cpa * 2.9f;
        float bb = cpb * 6.5f;
        float aa = fmaxf(a, 0.0f) + 0.1f;
        float th = fmaxf(bb, 0.0f) + 0.5f;
        float am1 = aa - 1.0f;
        float c1  = 1.4426950408889634f / th;  // log2(e)/theta
        const float L[LENF] = {  // log2(k + 0.5)
            -1.0f, 0.5849625007f, 1.3219280949f, 1.8073549221f, 2.1699250014f,
            2.4594316186f, 2.7004397181f, 2.9068905956f, 3.0874628413f, 3.2479275134f,
            3.3923174228f, 3.5235619561f, 3.6438561898f, 3.7548875022f, 3.8579809951f};
        float s = 0.0f;
        #pragma unroll
        for (int k = 0; k < LENF; ++k) {
            float tt = (float)k + 0.5f;
            float w = fexp2(fmaf(am1, L[k], -tt * c1));  // t^(aa-1) * exp(-t/theta)
            uh[k] = w;
            s += w;
        }
        float is = 1.0f / s;
        #pragma unroll
        for (int k = 0; k < LENF; ++k) uh[k] *= is;
    }

    __syncthreads();

    // ---- parallel routing conv: lane m covers a contiguous 4-aligned t-chunk.
    // Invariant at each t: w[1..14] = qsum(t-1..t-14); w[0] set from qs<tl>.
    const int chunk = (((Nstep + 15) >> 4) + 3) & ~3;   // 24 for Nstep=365
    const int t0 = m * chunk;
    const int t1 = min(t0 + chunk, Nstep);

    float w[LENF];
    #pragma unroll
    for (int k = 1; k < LENF; ++k) {
        int tt = t0 - k;
        if (tt >= 0) {
            const float* qp = qbuf + (tt >> 2) * 64 + gl * 16 + (tt & 3);
            w[k] = ((qp[0] + qp[4]) + (qp[8] + qp[12])) * 0.0625f;
        } else {
            w[k] = 0.0f;
        }
    }

    for (int tc = t0; tc < t1; tc += 4) {
        const float4* qp = (const float4*)qbuf + (tc >> 2) * 16 + gl * 4;
        float4 s0 = qp[0], s1 = qp[1], s2 = qp[2], s3 = qp[3];
        float qs0 = ((s0.x + s1.x) + (s2.x + s3.x)) * 0.0625f;
        float qs1 = ((s0.y + s1.y) + (s2.y + s3.y)) * 0.0625f;
        float qs2 = ((s0.z + s1.z) + (s2.z + s3.z)) * 0.0625f;
        float qs3 = ((s0.w + s1.w) + (s2.w + s3.w)) * 0.0625f;

        #define CONV_ONE(QS, TT)                                            \
        {                                                                   \
            w[0] = (QS);                                                    \
            float acc = 0.0f;                                               \
            _Pragma("unroll")                                               \
            for (int k = 0; k < LENF; ++k) acc = fmaf(uh[k], w[k], acc);    \
            out[(size_t)(TT) * Ngrid + g] = acc;                            \
            _Pragma("unroll")                                               \
            for (int k = LENF - 1; k > 0; --k) w[k] = w[k - 1];             \
        }

        CONV_ONE(qs0, tc);
        if (tc + 1 < t1) CONV_ONE(qs1, tc + 1);
        if (tc + 2 < t1) CONV_ONE(qs2, tc + 2);
        if (tc + 3 < t1) CONV_ONE(qs3, tc + 3);
        #undef CONV_ONE
    }
}

extern "C" void kernel_launch(void* const* d_in, const int* in_sizes, int n_in,
                              void* d_out, int out_size, void* d_ws, size_t ws_size,
                              hipStream_t stream) {
    const float* x     = (const float*)d_in[0];
    // d_in[1] = c_hydro_model — unused by the reference
    const float* praw  = (const float*)d_in[2];
    const float* convp = (const float*)d_in[3];
    float* out = (float*)d_out;

    int Ngrid = in_sizes[3] / 2;                 // conv_params_hydro: [Ngrid, 2]
    int Nstep = in_sizes[0] / (3 * Ngrid);       // x: [Nstep, Ngrid, 3]
    int blocks = Ngrid / 4;                      // 4 grids per 64-thread block

    hbv_kernel<<<blocks, 64, 0, stream>>>(x, praw, convp, out, Nstep, Ngrid);
}